// Round 3
// baseline (112.579 us; speedup 1.0000x reference)
//
#include <hip/hip_runtime.h>

// T=256 frames, 20 boxes. Output (1, 5120, 5120) fp32 block-diagonal:
// diagonal block d holds iou(rois[d+1], rois[d+2]) for d in [0,254),
// block 255 holds iou(rois[0], rois[1]), block 254 is zero.
// Reference bug preserved: area_b uses b[...,2] in BOTH factors.
//
// Store-BW-bound: 104.9 MB written exactly once. Round-1 result: per-wave
// MLP / workgroup-count restructure was exactly neutral -> residual time is
// pattern-invariant. This round probes the cache path: the harness's poison
// fill leaves the whole output dirty in L2/LLC right before we run; plain
// stores then pay dirty-line writeback interaction. Non-temporal stores
// (global_store_dwordx4 nt) stream past that. (Round-2 fix: the builtin
// needs a clang native vector type, not HIP's float4 class.)

#define TT 256
#define NB 20
#define DIM (TT * NB)      // 5120 floats per row
#define DIM4 (DIM / 4)     // 1280 float4 per row
#define RPB 4              // rows per block; 4 | 20 so kr is block-uniform

typedef float floatx4 __attribute__((ext_vector_type(4)));

__global__ void __launch_bounds__(256) fused_iou_diag_kernel(
        const float4* __restrict__ rois, float4* __restrict__ out) {
    const int wave = threadIdx.x >> 6;          // 0..3 -> which row of the 4
    const int lane = threadIdx.x & 63;
    const int row  = blockIdx.x * RPB + wave;   // 0..5119
    const int kr   = row / NB;                  // diagonal block index
    const int ri   = row - kr * NB;             // row within block

    const bool active = (kr != 254);
    const int t  = (kr == 255) ? 0 : kr + 1;    // a = rois[t], b = rois[t+1]
    const int tb = active ? t + 1 : 0;          // keep pointer math in-bounds

    const float4 a = rois[t * NB + ri];         // wave-broadcast load
    const float area_a = (a.z - a.x + 1.f) * (a.w - a.y + 1.f);

    const int bcol0 = kr * (NB / 4);            // first in-block float4 column
    const float4* brow = rois + tb * NB;
    floatx4* rowp = (floatx4*)(out + (size_t)row * DIM4);

    #pragma unroll
    for (int k = 0; k < DIM4 / 64; ++k) {       // 20 float4 stores per thread
        const int c4 = (k << 6) + lane;
        floatx4 v = (floatx4)(0.f);
        const int j4 = c4 - bcol0;
        if (active && (unsigned)j4 < (unsigned)(NB / 4)) {
            #pragma unroll
            for (int q = 0; q < 4; ++q) {
                const float4 b = brow[j4 * 4 + q];
                const float ix1 = fmaxf(a.x, b.x);
                const float ix2 = fminf(a.z, b.z);
                const float iy1 = fmaxf(a.y, b.y);
                const float iy2 = fminf(a.w, b.w);
                const float inter =
                    fmaxf(ix2 - ix1, 0.f) * fmaxf(iy2 - iy1, 0.f);
                // reference bug preserved: b.z in both factors
                const float area_b = (b.z - b.x + 1.f) * (b.z - b.y + 1.f);
                v[q] = inter / (area_a + area_b - inter);
            }
        }
        __builtin_nontemporal_store(v, &rowp[c4]);
    }
}

extern "C" void kernel_launch(void* const* d_in, const int* in_sizes, int n_in,
                              void* d_out, int out_size, void* d_ws, size_t ws_size,
                              hipStream_t stream) {
    const float4* rois = (const float4*)d_in[0];
    float4* out = (float4*)d_out;
    fused_iou_diag_kernel<<<DIM / RPB, 256, 0, stream>>>(rois, out);
}

// Round 4
// 108.216 us; speedup vs baseline: 1.0403x; 1.0403x over previous
//
#include <hip/hip_runtime.h>

// T=256 frames, 20 boxes. Output (1, 5120, 5120) fp32 block-diagonal:
// diagonal block d holds iou(rois[d+1], rois[d+2]) for d in [0,254),
// block 255 holds iou(rois[0], rois[1]), block 254 is zero.
// Reference bug preserved: area_b uses b[...,2] in BOTH factors.
//
// Rounds 0-3: every store-path variant (1 vs 4 rows/block, 4x per-wave MLP,
// nontemporal stores) was exactly neutral at ~107 us total. This round
// replaces the bulk-zero write (98.4% of the 104.9 MB output) with
// hipMemsetAsync -- the same rocclr fill path the harness's poison uses,
// measured at 6.4 TB/s on this exact buffer (~16.5 us for 105 MB) -- plus a
// tiny kernel writing only the 255 diagonal 20x20 blocks (408 KB).

#define TT 256
#define NB 20
#define DIM (TT * NB)      // 5120 floats per row
#define DIM4 (DIM / 4)     // 1280 float4 per row

__global__ void __launch_bounds__(128) diag_iou_kernel(
        const float4* __restrict__ rois, float4* __restrict__ out) {
    // blockIdx.x in [0,255): diagonal blocks 0..253 and 255 (254 stays zero)
    const int bid = blockIdx.x;
    const int kr  = (bid == 254) ? 255 : bid;     // diagonal block index
    const int t   = (kr == 255) ? 0 : kr + 1;     // a = rois[t], b = rois[t+1]

    const int tid = threadIdx.x;                  // 0..127, use 100
    if (tid >= 100) return;
    const int ri = tid / 5;                       // row within block, 0..19
    const int j4 = tid % 5;                       // float4 column, 0..4

    const float4 a = rois[t * NB + ri];
    const float area_a = (a.z - a.x + 1.f) * (a.w - a.y + 1.f);
    const float4* brow = rois + (t + 1) * NB;

    float4 v;
    float* vp = (float*)&v;
    #pragma unroll
    for (int q = 0; q < 4; ++q) {
        const float4 b = brow[j4 * 4 + q];
        const float ix1 = fmaxf(a.x, b.x);
        const float ix2 = fminf(a.z, b.z);
        const float iy1 = fmaxf(a.y, b.y);
        const float iy2 = fminf(a.w, b.w);
        const float inter = fmaxf(ix2 - ix1, 0.f) * fmaxf(iy2 - iy1, 0.f);
        // reference bug preserved: b.z in both factors
        const float area_b = (b.z - b.x + 1.f) * (b.z - b.y + 1.f);
        vp[q] = inter / (area_a + area_b - inter);
    }

    const int row = kr * NB + ri;
    out[(size_t)row * DIM4 + kr * 5 + j4] = v;
}

extern "C" void kernel_launch(void* const* d_in, const int* in_sizes, int n_in,
                              void* d_out, int out_size, void* d_ws, size_t ws_size,
                              hipStream_t stream) {
    const float4* rois = (const float4*)d_in[0];
    float4* out = (float4*)d_out;
    // Bulk zero via the rocclr fill path (graph-capturable memset node).
    hipMemsetAsync(d_out, 0, (size_t)DIM * DIM * sizeof(float), stream);
    // Then overwrite the 255 diagonal 20x20 blocks.
    diag_iou_kernel<<<255, 128, 0, stream>>>(rois, out);
}